// Round 1
// baseline (233.052 us; speedup 1.0000x reference)
//
#include <hip/hip_runtime.h>

typedef _Float16 h8_t __attribute__((ext_vector_type(8)));
typedef _Float16 h4_t __attribute__((ext_vector_type(4)));
typedef float f32x4 __attribute__((ext_vector_type(4)));

#define NB 64
#define NH 8
#define NL 2048
#define ND 512
// rows of the flat K matrix: NB*NL = 131072

// ---------------- Kernel 1: Wq = Q @ Ww.T + Wb  (f32, tiny) ----------------
__global__ __launch_bounds__(256) void wq_kernel(const float* __restrict__ Q,
                                                 const float* __restrict__ Ww,
                                                 const float* __restrict__ Wb,
                                                 float* __restrict__ Wq) {
    __shared__ float q[ND];
    const int b = blockIdx.x;
    const int t = threadIdx.x;
    for (int i = t; i < ND; i += 256) q[i] = Q[b * ND + i];
    __syncthreads();
    for (int j = t; j < ND; j += 256) {
        const float* wr = Ww + (size_t)j * ND;
        float acc = 0.f;
        for (int k = 0; k < ND; k += 4) {
            float4 w = *(const float4*)(wr + k);
            acc += q[k] * w.x + q[k + 1] * w.y + q[k + 2] * w.z + q[k + 3] * w.w;
        }
        Wq[b * ND + j] = acc + Wb[j];
    }
}

// ---------------- Kernel 2: convert Uw (f32) -> fp16 ----------------
__global__ __launch_bounds__(256) void cvt_uw_kernel(const float* __restrict__ Uw,
                                                     _Float16* __restrict__ UwH) {
    const size_t i = ((size_t)blockIdx.x * 256 + threadIdx.x) * 4;
    float4 v = *(const float4*)(Uw + i);
    h4_t h = {(_Float16)v.x, (_Float16)v.y, (_Float16)v.z, (_Float16)v.w};
    *(h4_t*)(UwH + i) = h;
}

// ---------------- Kernel 3: Uk GEMM (fp16 MFMA) + tanh-reduce -> scores ----------------
// A = K (131072 x 512, f32 -> fp16 on stage), B^T = UwH (512 x 512 row-major, k-contiguous)
// tile: BM=128, BN=128, BK=64; 4 waves, each 64x64.
#define LDP 72  // padded LDS row stride (halfs); 144B -> conflict-light

__global__ __launch_bounds__(256) void uk_score_kernel(
    const float* __restrict__ Km,       // [131072][512]
    const _Float16* __restrict__ UwH,   // [512][512]
    const float* __restrict__ Ub,       // [512]
    const float* __restrict__ Wq,       // [64][512]
    const float* __restrict__ Vw,       // [64]
    const float* __restrict__ Vb,       // [1]
    float* __restrict__ scores)         // [512][2048]
{
    __shared__ _Float16 Al[128][LDP];
    __shared__ _Float16 Bl[128][LDP];

    const int t = threadIdx.x;
    const int lane = t & 63;
    const int wave = t >> 6;          // 0..3
    const int wm = wave >> 1;         // 0..1
    const int wn = wave & 1;          // 0..1

    // XCD-aware swizzle: keep the 4 n-tiles of one m-tile on the same XCD (A-tile L2 reuse)
    const int bid = blockIdx.x;
    const int swz = (bid & 7) * 512 + (bid >> 3);   // 4096 blocks, bijective
    const int tn = swz & 3;
    const int tm = swz >> 2;
    const size_t row0 = (size_t)tm * 128;
    const int n0 = tn * 128;

    f32x4 acc[4][4];
#pragma unroll
    for (int i = 0; i < 4; ++i)
#pragma unroll
        for (int j = 0; j < 4; ++j) acc[i][j] = (f32x4){0.f, 0.f, 0.f, 0.f};

    const int ar = t >> 4;            // 0..15
    const int ac = (t & 15) * 4;      // 0..60
    const int br = t >> 3;            // 0..31
    const int bc = (t & 7) * 8;       // 0..56

    for (int kk = 0; kk < ND; kk += 64) {
        // stage A: 128x64 f32 -> fp16
        const float* ga = Km + (row0 + ar) * (size_t)ND + kk + ac;
#pragma unroll
        for (int it = 0; it < 8; ++it) {
            float4 v = *(const float4*)(ga + (size_t)it * 16 * ND);
            h4_t h = {(_Float16)v.x, (_Float16)v.y, (_Float16)v.z, (_Float16)v.w};
            *(h4_t*)&Al[ar + it * 16][ac] = h;
        }
        // stage B: 128x64 fp16 (pre-converted)
        const _Float16* gb = UwH + (size_t)(n0 + br) * ND + kk + bc;
#pragma unroll
        for (int it = 0; it < 4; ++it) {
            h8_t v = *(const h8_t*)(gb + (size_t)it * 32 * ND);
            *(h8_t*)&Bl[br + it * 32][bc] = v;
        }
        __syncthreads();
#pragma unroll
        for (int ks = 0; ks < 2; ++ks) {
            const int krd = ks * 32 + (lane >> 4) * 8;
            h8_t af[4], bf[4];
#pragma unroll
            for (int i = 0; i < 4; ++i)
                af[i] = *(const h8_t*)&Al[wm * 64 + i * 16 + (lane & 15)][krd];
#pragma unroll
            for (int j = 0; j < 4; ++j)
                bf[j] = *(const h8_t*)&Bl[wn * 64 + j * 16 + (lane & 15)][krd];
#pragma unroll
            for (int i = 0; i < 4; ++i)
#pragma unroll
                for (int j = 0; j < 4; ++j)
                    acc[i][j] = __builtin_amdgcn_mfma_f32_16x16x32_f16(af[i], bf[j], acc[i][j], 0, 0, 0);
        }
        __syncthreads();
    }

    // epilogue: score(row, jb) = sum_dh tanh(Uk + Wq + Ub) * Vw  (+Vb)
    const int b = (int)(row0 >> 11);
    const int h = ((int)row0 >> 8) & 7;
    const int i256b = (int)row0 & 255;
    const int col16 = lane & 15;

    float vw[4], wqv[4], ubv[4];
#pragma unroll
    for (int j = 0; j < 4; ++j) {
        const int jglob = n0 + wn * 64 + j * 16 + col16;  // 0..511
        const int dh = jglob & 63;
        vw[j] = Vw[dh];
        wqv[j] = Wq[b * ND + h * 64 + dh];
        ubv[j] = Ub[jglob];
    }
    const float vb0 = Vb[0];
    const int jb = (n0 + wn * 64) >> 6;  // 0..7
    const int bh = b * 8 + h;

#pragma unroll
    for (int i = 0; i < 4; ++i) {
#pragma unroll
        for (int r = 0; r < 4; ++r) {
            float s = 0.f;
#pragma unroll
            for (int j = 0; j < 4; ++j) {
                float x = acc[i][j][r] + wqv[j] + ubv[j];
                x = fminf(fmaxf(x, -15.f), 15.f);
                float e = __expf(2.f * x);
                s += ((e - 1.f) / (e + 1.f)) * vw[j];
            }
#pragma unroll
            for (int o = 8; o >= 1; o >>= 1) s += __shfl_xor(s, o);
            if (col16 == 0) {
                const int rloc = wm * 64 + i * 16 + (lane >> 4) * 4 + r;
                const int m = (i256b + rloc) * 8 + jb;
                scores[(size_t)bh * NL + m] = s + vb0;
            }
        }
    }
}

// ---------------- Kernel 4: softmax -> dist (out) + attn = dist @ Kh ----------------
__global__ __launch_bounds__(256) void softmax_attn_kernel(
    const float* __restrict__ Km,
    const float* __restrict__ scores,
    float* __restrict__ out)  // [0,32768) attn, [32768,...) dist
{
    __shared__ float sd[NL];
    __shared__ float red[256];
    __shared__ float att[16][64];

    const int bh = blockIdx.x;
    const int b = bh >> 3, h = bh & 7;
    const int t = threadIdx.x;

    float loc[8];
    float mx = -1e30f;
#pragma unroll
    for (int j = 0; j < 8; ++j) {
        loc[j] = scores[(size_t)bh * NL + j * 256 + t];
        mx = fmaxf(mx, loc[j]);
    }
    red[t] = mx;
    __syncthreads();
    for (int s2 = 128; s2 > 0; s2 >>= 1) {
        if (t < s2) red[t] = fmaxf(red[t], red[t + s2]);
        __syncthreads();
    }
    mx = red[0];
    __syncthreads();
    float sum = 0.f;
#pragma unroll
    for (int j = 0; j < 8; ++j) {
        loc[j] = __expf(loc[j] - mx);
        sum += loc[j];
    }
    red[t] = sum;
    __syncthreads();
    for (int s2 = 128; s2 > 0; s2 >>= 1) {
        if (t < s2) red[t] += red[t + s2];
        __syncthreads();
    }
    const float inv = 1.f / red[0];
    __syncthreads();

    float* dist_out = out + 32768 + (size_t)bh * NL;
#pragma unroll
    for (int j = 0; j < 8; ++j) {
        float d = loc[j] * inv;
        sd[j * 256 + t] = d;
        dist_out[j * 256 + t] = d;
    }
    __syncthreads();

    // attn[dh] = sum over 256 rows x 8 chunks of dist[row*8+jb] * K[b, h*256+row, jb*64+dh]
    const int wave = t >> 6, lane = t & 63;
    const int g = lane >> 4;           // row sub-stream 0..3
    const int c4 = (lane & 15) * 4;    // dh base
    f32x4 acc = (f32x4){0.f, 0.f, 0.f, 0.f};
    const float* kb = Km + ((size_t)b * NL + h * 256) * ND;
    for (int rr = 0; rr < 16; ++rr) {
        const int row = wave * 64 + rr * 4 + g;
        const float* kr = kb + (size_t)row * ND;
#pragma unroll
        for (int jb2 = 0; jb2 < 8; ++jb2) {
            const float w = sd[row * 8 + jb2];
            float4 v = *(const float4*)(kr + jb2 * 64 + c4);
            acc[0] += w * v.x;
            acc[1] += w * v.y;
            acc[2] += w * v.z;
            acc[3] += w * v.w;
        }
    }
    *(f32x4*)&att[wave * 4 + g][c4] = acc;
    __syncthreads();
    if (t < 64) {
        float a = 0.f;
#pragma unroll
        for (int i = 0; i < 16; ++i) a += att[i][t];
        out[(size_t)b * ND + h * 64 + t] = a;
    }
}

extern "C" void kernel_launch(void* const* d_in, const int* in_sizes, int n_in,
                              void* d_out, int out_size, void* d_ws, size_t ws_size,
                              hipStream_t stream) {
    const float* Q  = (const float*)d_in[0];
    const float* Km = (const float*)d_in[1];
    const float* Ww = (const float*)d_in[2];
    const float* Wb = (const float*)d_in[3];
    const float* Uw = (const float*)d_in[4];
    const float* Ub = (const float*)d_in[5];
    const float* Vw = (const float*)d_in[6];
    const float* Vb = (const float*)d_in[7];
    float* out = (float*)d_out;

    char* ws = (char*)d_ws;
    float* scores = (float*)ws;                              // 512*2048*4 = 4 MB
    float* Wq = (float*)(ws + 4194304);                      // 64*512*4 = 128 KB
    _Float16* UwH = (_Float16*)(ws + 4194304 + 131072);      // 512*512*2 = 512 KB

    wq_kernel<<<dim3(64), dim3(256), 0, stream>>>(Q, Ww, Wb, Wq);
    cvt_uw_kernel<<<dim3(256), dim3(256), 0, stream>>>(Uw, UwH);
    uk_score_kernel<<<dim3(4096), dim3(256), 0, stream>>>(Km, UwH, Ub, Wq, Vw, Vb, scores);
    softmax_attn_kernel<<<dim3(512), dim3(256), 0, stream>>>(Km, scores, out);
}

// Round 2
// 191.056 us; speedup vs baseline: 1.2198x; 1.2198x over previous
//
#include <hip/hip_runtime.h>

typedef _Float16 h8_t __attribute__((ext_vector_type(8)));
typedef _Float16 h4_t __attribute__((ext_vector_type(4)));
typedef float f32x4 __attribute__((ext_vector_type(4)));

#define NB 64
#define NH 8
#define NL 2048
#define ND 512
// flat K matrix rows: NB*NL = 131072

#define GLD_LDS16(g, l) \
    __builtin_amdgcn_global_load_lds((const __attribute__((address_space(1))) unsigned int*)(g), \
                                     (__attribute__((address_space(3))) unsigned int*)(l), 16, 0, 0)

// swizzled half-index into a [rows][32]-fp16 tile: XOR 16B-chunk with row bits
__device__ __forceinline__ int swz_idx(int row, int chunk) {
    return row * 32 + ((chunk ^ ((row >> 1) & 3)) << 3);
}

// ---------------- Kernel 1: Wq = Q @ Ww.T + Wb  (f32, tiny) ----------------
__global__ __launch_bounds__(256) void wq_kernel(const float* __restrict__ Q,
                                                 const float* __restrict__ Ww,
                                                 const float* __restrict__ Wb,
                                                 float* __restrict__ Wq) {
    __shared__ float q[ND];
    const int b = blockIdx.x;
    const int t = threadIdx.x;
    for (int i = t; i < ND; i += 256) q[i] = Q[b * ND + i];
    __syncthreads();
    for (int j = t; j < ND; j += 256) {
        const float* wr = Ww + (size_t)j * ND;
        float acc = 0.f;
        for (int k = 0; k < ND; k += 4) {
            float4 w = *(const float4*)(wr + k);
            acc += q[k] * w.x + q[k + 1] * w.y + q[k + 2] * w.z + q[k + 3] * w.w;
        }
        Wq[b * ND + j] = acc + Wb[j];
    }
}

// ---------------- Kernel 2: convert Uw (f32) -> fp16 (RNE) ----------------
__global__ __launch_bounds__(256) void cvt_uw_kernel(const float* __restrict__ Uw,
                                                     _Float16* __restrict__ UwH) {
    const size_t i = ((size_t)blockIdx.x * 256 + threadIdx.x) * 4;
    float4 v = *(const float4*)(Uw + i);
    h4_t h = {(_Float16)v.x, (_Float16)v.y, (_Float16)v.z, (_Float16)v.w};
    *(h4_t*)(UwH + i) = h;
}

// ---------------- Kernel 3: Uk GEMM (fp16 MFMA) + tanh-reduce -> scores ----------------
// BM=128, BN=256, BK=32, 8 waves (2m x 4n), each wave 64x64 output.
// A (K rows, f32) reg-staged + converted + swizzled ds_write_b128.
// B (UwH fp16) staged via global_load_lds with pre-swizzled global source.
__global__ __launch_bounds__(512, 4) void uk_score_kernel(
    const float* __restrict__ Km,       // [131072][512] f32
    const _Float16* __restrict__ UwH,   // [512][512] fp16
    const float* __restrict__ Ub,       // [512]
    const float* __restrict__ Wq,       // [64][512]
    const float* __restrict__ Vw,       // [64]
    const float* __restrict__ Vb,       // [1]
    float* __restrict__ scores)         // [512][2048]
{
    __shared__ __align__(16) _Float16 Al[128 * 32];   // 8 KB
    __shared__ __align__(16) _Float16 Bl[256 * 32];   // 16 KB

    const int t = threadIdx.x;
    const int lane = t & 63;
    const int wave = t >> 6;          // 0..7
    const int wm = wave >> 2;         // 0..1
    const int wn = wave & 3;          // 0..3

    // XCD swizzle: the 2 n-tiles of one m-tile land consecutively on one XCD (A L2 reuse)
    const int bid = blockIdx.x;                      // 2048 blocks
    const int swz = (bid & 7) * 256 + (bid >> 3);    // bijective
    const int tn = swz & 1;
    const int tm = swz >> 1;                         // 0..1023
    const size_t row0 = (size_t)tm * 128;
    const int n0 = tn * 256;

    f32x4 acc[4][4];
#pragma unroll
    for (int i = 0; i < 4; ++i)
#pragma unroll
        for (int j = 0; j < 4; ++j) acc[i][j] = (f32x4){0.f, 0.f, 0.f, 0.f};

    // A staging: thread t loads 8 consecutive floats of row (t>>2), chunk (t&3)
    const int arow = t >> 2;
    const int achunk = t & 3;
    const float* gA = Km + (row0 + arow) * (size_t)ND + achunk * 8;
    _Float16* aw = &Al[swz_idx(arow, achunk)];

    const int col16 = lane & 15;
    const int kg = lane >> 4;

    for (int kk = 0; kk < ND; kk += 32) {
        // A: global f32 -> regs (issue before barrier; latency overlaps)
        const float4 v0 = *(const float4*)(gA + kk);
        const float4 v1 = *(const float4*)(gA + kk + 4);
        __syncthreads();   // previous tile fully consumed
        // B: direct-to-LDS DMA, source pre-swizzled so LDS lands XOR-swizzled
#pragma unroll
        for (int it = 0; it < 2; ++it) {
            const int slot = it * 512 + t;
            const int brow = slot >> 2;
            const int bc = (slot & 3) ^ ((brow >> 1) & 3);
            const _Float16* gb = UwH + (size_t)(n0 + brow) * ND + kk + bc * 8;
            GLD_LDS16(gb, (char*)Bl + (it * 512 + (t & ~63)) * 16);
        }
        // A: cvt (RNE) + one swizzled ds_write_b128
        h8_t ah = {(_Float16)v0.x, (_Float16)v0.y, (_Float16)v0.z, (_Float16)v0.w,
                   (_Float16)v1.x, (_Float16)v1.y, (_Float16)v1.z, (_Float16)v1.w};
        *(h8_t*)aw = ah;
        __syncthreads();   // compiler drains vmcnt+lgkmcnt here

        h8_t af[4], bf[4];
#pragma unroll
        for (int i = 0; i < 4; ++i)
            af[i] = *(const h8_t*)&Al[swz_idx(wm * 64 + i * 16 + col16, kg)];
#pragma unroll
        for (int j = 0; j < 4; ++j)
            bf[j] = *(const h8_t*)&Bl[swz_idx(wn * 64 + j * 16 + col16, kg)];
#pragma unroll
        for (int i = 0; i < 4; ++i)
#pragma unroll
            for (int j = 0; j < 4; ++j)
                acc[i][j] = __builtin_amdgcn_mfma_f32_16x16x32_f16(af[i], bf[j], acc[i][j], 0, 0, 0);
    }

    // epilogue: score(row, jb) = sum_dh tanh(Uk + Wq + Ub) * Vw  (+Vb)
    const int b = (int)(row0 >> 11);
    const int h = ((int)row0 >> 8) & 7;
    const int i256b = (int)row0 & 255;

    float vw[4], wqv[4], ubv[4];
#pragma unroll
    for (int j = 0; j < 4; ++j) {
        const int jglob = n0 + wn * 64 + j * 16 + col16;  // 0..511
        const int dh = jglob & 63;
        vw[j] = Vw[dh];
        wqv[j] = Wq[b * ND + h * 64 + dh];
        ubv[j] = Ub[jglob];
    }
    const float vb0 = Vb[0];
    const int jb = tn * 4 + wn;       // 0..7
    const int bh = b * 8 + h;

#pragma unroll
    for (int i = 0; i < 4; ++i) {
#pragma unroll
        for (int r = 0; r < 4; ++r) {
            float s = 0.f;
#pragma unroll
            for (int j = 0; j < 4; ++j) {
                float x = acc[i][j][r] + wqv[j] + ubv[j];
                x = fminf(fmaxf(x, -15.f), 15.f);
                float e = __expf(2.f * x);
                s += ((e - 1.f) / (e + 1.f)) * vw[j];
            }
#pragma unroll
            for (int o = 8; o >= 1; o >>= 1) s += __shfl_xor(s, o);
            if (col16 == 0) {
                const int rloc = wm * 64 + i * 16 + (lane >> 4) * 4 + r;
                const int m = (i256b + rloc) * 8 + jb;
                scores[(size_t)bh * NL + m] = s + vb0;
            }
        }
    }
}

// ---------------- Kernel 4: softmax -> dist (out) + attn = dist @ Kh ----------------
__global__ __launch_bounds__(256) void softmax_attn_kernel(
    const float* __restrict__ Km,
    const float* __restrict__ scores,
    float* __restrict__ out)  // [0,32768) attn, [32768,...) dist
{
    __shared__ float sd[NL];
    __shared__ float red[256];
    __shared__ float att[16][64];

    const int bh = blockIdx.x;
    const int b = bh >> 3, h = bh & 7;
    const int t = threadIdx.x;

    float loc[8];
    float mx = -1e30f;
#pragma unroll
    for (int j = 0; j < 8; ++j) {
        loc[j] = scores[(size_t)bh * NL + j * 256 + t];
        mx = fmaxf(mx, loc[j]);
    }
    red[t] = mx;
    __syncthreads();
    for (int s2 = 128; s2 > 0; s2 >>= 1) {
        if (t < s2) red[t] = fmaxf(red[t], red[t + s2]);
        __syncthreads();
    }
    mx = red[0];
    __syncthreads();
    float sum = 0.f;
#pragma unroll
    for (int j = 0; j < 8; ++j) {
        loc[j] = __expf(loc[j] - mx);
        sum += loc[j];
    }
    red[t] = sum;
    __syncthreads();
    for (int s2 = 128; s2 > 0; s2 >>= 1) {
        if (t < s2) red[t] += red[t + s2];
        __syncthreads();
    }
    const float inv = 1.f / red[0];
    __syncthreads();

    float* dist_out = out + 32768 + (size_t)bh * NL;
#pragma unroll
    for (int j = 0; j < 8; ++j) {
        float d = loc[j] * inv;
        sd[j * 256 + t] = d;
        dist_out[j * 256 + t] = d;
    }
    __syncthreads();

    const int wave = t >> 6, lane = t & 63;
    const int g = lane >> 4;
    const int c4 = (lane & 15) * 4;
    f32x4 acc = (f32x4){0.f, 0.f, 0.f, 0.f};
    const float* kb = Km + ((size_t)b * NL + h * 256) * ND;
    for (int rr = 0; rr < 16; ++rr) {
        const int row = wave * 64 + rr * 4 + g;
        const float* kr = kb + (size_t)row * ND;
#pragma unroll
        for (int jb2 = 0; jb2 < 8; ++jb2) {
            const float w = sd[row * 8 + jb2];
            float4 v = *(const float4*)(kr + jb2 * 64 + c4);
            acc[0] += w * v.x;
            acc[1] += w * v.y;
            acc[2] += w * v.z;
            acc[3] += w * v.w;
        }
    }
    *(f32x4*)&att[wave * 4 + g][c4] = acc;
    __syncthreads();
    if (t < 64) {
        float a = 0.f;
#pragma unroll
        for (int i = 0; i < 16; ++i) a += att[i][t];
        out[(size_t)b * ND + h * 64 + t] = a;
    }
}

extern "C" void kernel_launch(void* const* d_in, const int* in_sizes, int n_in,
                              void* d_out, int out_size, void* d_ws, size_t ws_size,
                              hipStream_t stream) {
    const float* Q  = (const float*)d_in[0];
    const float* Km = (const float*)d_in[1];
    const float* Ww = (const float*)d_in[2];
    const float* Wb = (const float*)d_in[3];
    const float* Uw = (const float*)d_in[4];
    const float* Ub = (const float*)d_in[5];
    const float* Vw = (const float*)d_in[6];
    const float* Vb = (const float*)d_in[7];
    float* out = (float*)d_out;

    char* ws = (char*)d_ws;
    float* scores = (float*)ws;                              // 4 MB
    float* Wq = (float*)(ws + 4194304);                      // 128 KB
    _Float16* UwH = (_Float16*)(ws + 4194304 + 131072);      // 512 KB

    wq_kernel<<<dim3(64), dim3(256), 0, stream>>>(Q, Ww, Wb, Wq);
    cvt_uw_kernel<<<dim3(256), dim3(256), 0, stream>>>(Uw, UwH);
    uk_score_kernel<<<dim3(2048), dim3(512), 0, stream>>>(Km, UwH, Ub, Wq, Vw, Vb, scores);
    softmax_attn_kernel<<<dim3(512), dim3(256), 0, stream>>>(Km, scores, out);
}